// Round 4
// baseline (189.183 us; speedup 1.0000x reference)
//
#include <hip/hip_runtime.h>
#include <cstdint>
#include <cstddef>

// (B,H,L,D,k) = (4,1,2048,512,4), SHIFTS = {1,2,4}
// Folded: out[(b,l,j),d] = sum_c v[c]*Qj[c,d]               (diff, K=512)
//                        + sum_{si,c} silu(v[c]*W[j,(c-s)%512]) * Psilu[si,c,d]  (K=1536)
// v = x[b,l-1] for j<3, x[b,l] for j==3.
// Round 7: GS tensor eliminated. K-walk reordered c-major (kt = f*8+cb) so the four
// K-tiles sharing x-columns run consecutively; silu A-tiles are produced in-register
// (reg-load XbfZ + silu + swizzled ds_write) during ph1 of the preceding step.
// Schedule skeleton = round-3's verified 2-barrier/step + counted vmcnt(4).
// Prep = convert_x + build_B only (~80 MB traffic).
#define D_DIM 512
#define L_DIM 2048
#define KB_DIM 2048    // 512 diff + 3*512 silu
#define NROWS_X 2049   // per-b rows in XbfZ; row 0 is zeros (the l=-1 pad)

typedef __bf16 bf16x8 __attribute__((ext_vector_type(8)));
typedef float  f32x4  __attribute__((ext_vector_type(4)));

__device__ __forceinline__ unsigned f2bf(float f) {
  unsigned u = __float_as_uint(f);
  u += 0x7FFF + ((u >> 16) & 1);   // RNE
  return u >> 16;
}
__device__ __forceinline__ float bf2f(unsigned short u) {
  return __uint_as_float(((unsigned)u) << 16);
}
__device__ __forceinline__ void gld_lds16(const void* g, void* l) {
  __builtin_amdgcn_global_load_lds((const __attribute__((address_space(1))) void*)g,
                                   (__attribute__((address_space(3))) void*)l,
                                   16, 0, 0);
}

// ---------------- prepass: x fp32 -> XbfZ bf16 (zero row 0 per b)  AND  build_B ------
// grid 2305 x 256: blocks [0,256) = build_B; blocks [256,2305) = convert (1 uint4/thr).
__global__ __launch_bounds__(256) void prep(
    const float* __restrict__ x, const float* __restrict__ W, const float* __restrict__ P,
    unsigned short* __restrict__ XbfZ, unsigned short* __restrict__ Ball) {
  const int tid = threadIdx.x;
  if (blockIdx.x >= 256) {
    const int u = (blockIdx.x - 256) * 256 + tid;   // over 4*2049*64 uint4 units
    const int b = u / (NROWS_X * 64);
    const int rr = (u >> 6) % NROWS_X;              // 0..2048 ; rr==0 -> zero row
    const int c8 = u & 63;
    uint4 p = {0u, 0u, 0u, 0u};
    if (rr > 0) {
      const float4* src = reinterpret_cast<const float4*>(x) +
                          ((size_t)(b * L_DIM + rr - 1)) * 128 + c8 * 2;
      const float4 v0 = src[0], v1 = src[1];
      p.x = f2bf(v0.x) | (f2bf(v0.y) << 16);
      p.y = f2bf(v0.z) | (f2bf(v0.w) << 16);
      p.z = f2bf(v1.x) | (f2bf(v1.y) << 16);
      p.w = f2bf(v1.z) | (f2bf(v1.w) << 16);
    }
    reinterpret_cast<uint4*>(XbfZ)[((size_t)(b * NROWS_X + rr)) * 64 + c8] = p;
    return;
  }
  // ---------------- build_B path (Ball) ----------------
  const int bx = blockIdx.x;             // 0..255
  const int j = bx >> 6, dt = (bx >> 3) & 7, ct = bx & 7;
  const int d = dt * 64 + (tid & 63);
  const int cbase = ct * 64 + (tid >> 6) * 16;
  unsigned short bufd[16];
  unsigned short bufs[3][16];
  #pragma unroll
  for (int cc = 0; cc < 16; ++cc) {
    const int c = cbase + cc;
    float qd = 0.f;
    #pragma unroll
    for (int si = 0; si < 3; ++si) {
      const int s = 1 << si;
      const int cm = (c - s) & 511, cp = (c + s) & 511;
      qd += W[j * 512 + cm] * P[((size_t)(2 * si) * 512 + c) * 512 + d]
          - W[j * 512 + cp] * P[((size_t)(2 * si) * 512 + cp) * 512 + d];
      bufs[si][cc] = (unsigned short)f2bf(P[((size_t)(2 * si + 1) * 512 + c) * 512 + d]);
    }
    bufd[cc] = (unsigned short)f2bf(qd);
  }
  unsigned short* row = Ball + (size_t)(j * 512 + d) * KB_DIM;
  *reinterpret_cast<uint4*>(&row[cbase])     = *reinterpret_cast<uint4*>(&bufd[0]);
  *reinterpret_cast<uint4*>(&row[cbase + 8]) = *reinterpret_cast<uint4*>(&bufd[8]);
  #pragma unroll
  for (int si = 0; si < 3; ++si) {
    *reinterpret_cast<uint4*>(&row[512 + si * 512 + cbase])     = *reinterpret_cast<uint4*>(&bufs[si][0]);
    *reinterpret_cast<uint4*>(&row[512 + si * 512 + cbase + 8]) = *reinterpret_cast<uint4*>(&bufs[si][8]);
  }
}

// ---------------- main GEMM: 256x256, BK=64, 8 waves, c-major K-walk, in-reg silu ----
#define BARR asm volatile("s_barrier" ::: "memory")
#define VMW(N) asm volatile("s_waitcnt vmcnt(" #N ")" ::: "memory")
#define LGKM0 asm volatile("s_waitcnt lgkmcnt(0)" ::: "memory")
#define KT(S) (((((S) & 3)) << 3) + ((S) >> 2))

#define READ_A(MH, BUF) do { \
  _Pragma("unroll") \
  for (int mf = 0; mf < 4; ++mf) { \
    a[mf][0] = __builtin_bit_cast(bf16x8, *reinterpret_cast<const uint4*>(&A_lds[BUF][aRow[mf] + (MH)*4096 + p0])); \
    a[mf][1] = __builtin_bit_cast(bf16x8, *reinterpret_cast<const uint4*>(&A_lds[BUF][aRow[mf] + (MH)*4096 + p1])); \
  } } while (0)

#define READ_B(NH, BUF, BB) do { \
  _Pragma("unroll") \
  for (int nf = 0; nf < 2; ++nf) { \
    BB[nf][0] = __builtin_bit_cast(bf16x8, *reinterpret_cast<const uint4*>(&B_lds[BUF][bRow[nf] + (NH)*2048 + p0])); \
    BB[nf][1] = __builtin_bit_cast(bf16x8, *reinterpret_cast<const uint4*>(&B_lds[BUF][bRow[nf] + (NH)*2048 + p1])); \
  } } while (0)

#define MFMA_Q(MH, NH, BB) do { \
  _Pragma("unroll") \
  for (int mf = 0; mf < 4; ++mf) { \
    _Pragma("unroll") \
    for (int nf = 0; nf < 2; ++nf) { \
      acc[(MH)*4+mf][(NH)*2+nf] = __builtin_amdgcn_mfma_f32_16x16x32_bf16(a[mf][0], BB[nf][0], acc[(MH)*4+mf][(NH)*2+nf], 0, 0, 0); \
      acc[(MH)*4+mf][(NH)*2+nf] = __builtin_amdgcn_mfma_f32_16x16x32_bf16(a[mf][1], BB[nf][1], acc[(MH)*4+mf][(NH)*2+nf], 0, 0, 0); \
    } } } while (0)

__global__ __launch_bounds__(512, 2) void gemmcs(
    const unsigned short* __restrict__ XbfZ, const unsigned short* __restrict__ Ball,
    const float* __restrict__ W, const float* __restrict__ bias,
    float* __restrict__ out) {
  // Each buffer: 256 rows x 64 cols bf16 = 32 KB (row = 128 B = 8 chunks of 16 B).
  // Chunk XOR swizzle: chunk c of row r stored at pos p = c ^ (r&7).
  __shared__ alignas(16) unsigned short A_lds[2][16384];
  __shared__ alignas(16) unsigned short B_lds[2][16384];
  __shared__ alignas(16) unsigned short Wt[1536];   // [si][c] = bf16(W[j,(c-2^si)&511])

  const int tid = threadIdx.x;
  // Bijective XCD swizzle (256 blocks, 8 XCDs): XCD x gets wids x*32..x*32+31.
  const int bid = blockIdx.x;
  const int wid = (bid & 7) * 32 + (bid >> 3);
  const int mtile = wid >> 1;            // 0..127
  const int ntile = wid & 1;             // 0..1
  const int j  = mtile >> 5;
  const int b  = (mtile >> 3) & 3;
  const int l0 = (mtile & 7) * 256;
  const int n0 = ntile * 256;

  // Wt fill (read-only after prologue barrier)
  for (int i = tid; i < 1536; i += 512) {
    const int si = i >> 9, c = i & 511;
    Wt[i] = (unsigned short)f2bf(W[j * 512 + ((c - (1 << si)) & 511)]);
  }

  // ---- staging geometry (gld_lds): slot s: row s>>3, pos s&7, chunk = pos^(row&7) ----
  const int srow = tid >> 3;             // 0..63
  const int c8   = (tid & 7) ^ (srow & 7);
  const unsigned short* pXd = XbfZ + ((size_t)(b * NROWS_X + (j == 3) + l0 + srow)) * 512 + c8 * 8;
  const unsigned short* pB  = Ball + ((size_t)(j * 512 + n0 + srow)) * KB_DIM + c8 * 8;
  const int ldsSlot = tid * 8;           // shorts; second slot at +4096

  auto stageXd = [&](int cb, int bufi) {   // 4 glds: A(diff) tile = XbfZ cols cb*64..+64
    #pragma unroll
    for (int h = 0; h < 2; ++h) {
      const unsigned short* s = pXd + (size_t)h * 128 * 512 + cb * 64;
      unsigned short* dst = &A_lds[bufi][h * 8192 + ldsSlot];
      gld_lds16(s, dst);
      gld_lds16(s + 64 * 512, dst + 4096);
    }
  };
  auto stageB = [&](int kt, int bufi) {    // 4 glds
    #pragma unroll
    for (int h = 0; h < 2; ++h) {
      const unsigned short* s = pB + (size_t)h * 128 * KB_DIM + kt * 64;
      unsigned short* dst = &B_lds[bufi][h * 8192 + ldsSlot];
      gld_lds16(s, dst);
      gld_lds16(s + 64 * KB_DIM, dst + 4096);
    }
  };

  // ---- produce geometry: thread owns row prow = tid>>1, 32-elem half phalf ----
  const int prow = tid >> 1;             // 0..255
  const int phalf = tid & 1;
  const unsigned short* pXr = XbfZ + ((size_t)(b * NROWS_X + (j == 3) + l0 + prow)) * 512 + phalf * 32;

  // ---- MFMA frag geometry: 8 waves 2(M) x 4(N); per-wave output 128x64 ----
  const int lane = tid & 63, wv = tid >> 6;
  const int wm = wv >> 2, wn = wv & 3;
  const int l16 = lane & 15, quad = lane >> 4;
  const int p0 = ((quad)     ^ (l16 & 7)) * 8;   // k-chunk ks=0 (after XOR swizzle)
  const int p1 = ((quad + 4) ^ (l16 & 7)) * 8;   // k-chunk ks=1
  int aRow[4], bRow[2];
  #pragma unroll
  for (int mf = 0; mf < 4; ++mf) aRow[mf] = (wm * 128 + mf * 16 + l16) * 64;
  #pragma unroll
  for (int nf = 0; nf < 2; ++nf) bRow[nf] = (wn * 64 + nf * 16 + l16) * 64;

  f32x4 acc[8][4];
  #pragma unroll
  for (int i = 0; i < 8; ++i)
    #pragma unroll
    for (int n = 0; n < 4; ++n)
      acc[i][n] = f32x4{0.f, 0.f, 0.f, 0.f};

  bf16x8 a[4][2], b0[2][2], b1[2][2];

  // ---- prologue: A(0)+B(0) complete, B(1)=kt8 in flight (4 youngest) ----
  stageXd(0, 0);
  stageB(KT(0), 0);
  stageB(KT(1), 1);
  LGKM0;           // Wt ds_writes drained before any wave reads them post-barrier
  VMW(4);          // A(0)+B(0) landed; B(1) still in flight
  BARR;

  // Steady state (step s, cur=s&1): K-tile kt(s) = (s&3)*8 + (s>>2)  [c-major walk]
  //   ph0: issue A(s+1) source: f(s+1)==0 -> stageXd(cb+1) glds into nxt;
  //        else reg-load x (4x uint4).  Read A-h0 + ALL B; MFMA (0,*).  BARR.
  //   ph1: if silu-produce: VMW(0) (x-regs + B(s+1) landed), silu -> ds_write A_nxt.
  //        stage B(s+2) -> cur.  Read A-h1; MFMA (1,*).  LGKM0; VMW(4); BARR.
  for (int s = 0; s < 32; ++s) {
    const int cur = s & 1, nxt = cur ^ 1;
    const int f1 = (s + 1) & 3;
    const int cb1 = (s + 1) >> 2;
    uint4 xv[4];
    // ---- phase 0 ----
    if (s < 31) {
      if (f1 == 0) {
        stageXd(cb1, nxt);
      } else {
        #pragma unroll
        for (int k = 0; k < 4; ++k)
          xv[k] = *reinterpret_cast<const uint4*>(pXr + cb1 * 64 + k * 8);
      }
    }
    READ_A(0, cur);
    READ_B(0, cur, b0);
    READ_B(1, cur, b1);
    __builtin_amdgcn_s_setprio(1);
    MFMA_Q(0, 0, b0);
    MFMA_Q(0, 1, b1);
    __builtin_amdgcn_s_setprio(0);
    BARR;
    // ---- phase 1 ----
    if (s < 31 && f1 != 0) {
      VMW(0);      // x-regs landed (B(s+1) older: also landed, no extra stall)
      const int si = f1 - 1;
      const int wtbase = si * 512 + cb1 * 64 + phalf * 32;
      #pragma unroll
      for (int k = 0; k < 4; ++k) {
        union UU { uint4 q; unsigned short sh[8]; } vv, ww;
        vv.q = xv[k];
        ww.q = *reinterpret_cast<const uint4*>(&Wt[wtbase + k * 8]);
        unsigned res[4];
        #pragma unroll
        for (int e = 0; e < 4; ++e) {
          float s0 = bf2f(vv.sh[2 * e])     * bf2f(ww.sh[2 * e]);
          float s1 = bf2f(vv.sh[2 * e + 1]) * bf2f(ww.sh[2 * e + 1]);
          float g0 = s0 * __builtin_amdgcn_rcpf(1.f + __expf(-s0));
          float g1 = s1 * __builtin_amdgcn_rcpf(1.f + __expf(-s1));
          res[e] = f2bf(g0) | (f2bf(g1) << 16);
        }
        const int lc = phalf * 4 + k;
        const int pos = lc ^ (prow & 7);
        uint4 ov = {res[0], res[1], res[2], res[3]};
        *reinterpret_cast<uint4*>(&A_lds[nxt][prow * 64 + pos * 8]) = ov;
      }
    }
    if (s + 2 < 32) stageB(KT(s + 2), cur);
    READ_A(1, cur);
    __builtin_amdgcn_s_setprio(1);
    MFMA_Q(1, 1, b1);
    MFMA_Q(1, 0, b0);
    __builtin_amdgcn_s_setprio(0);
    if (s < 30) {
      LGKM0;       // produce ds_writes drained before other waves read A_nxt
      VMW(4);      // A(s+1)/B(s+1) landed; B(s+2) = 4 youngest stays in flight
      BARR;
    } else if (s == 30) {
      LGKM0;
      VMW(0);      // tail: everything for step 31 must land
      BARR;
    }
  }

  // ---- epilogue: C/D col = lane&15 (N), row = quad*4+reg (M) ----
  #pragma unroll
  for (int nfg = 0; nfg < 4; ++nfg) {
    const int d = n0 + wn * 64 + nfg * 16 + l16;
    const float bv = bias[d];
    #pragma unroll
    for (int mfg = 0; mfg < 8; ++mfg) {
      const int lrow = l0 + wm * 128 + mfg * 16 + quad * 4;
      #pragma unroll
      for (int rg = 0; rg < 4; ++rg) {
        out[((size_t)(b * L_DIM + lrow + rg) * 4 + j) * D_DIM + d] = acc[mfg][nfg][rg] + bv;
      }
    }
  }
}

extern "C" void kernel_launch(void* const* d_in, const int* in_sizes, int n_in,
                              void* d_out, int out_size, void* d_ws, size_t ws_size,
                              hipStream_t stream) {
  const float* x    = (const float*)d_in[0];  // (4,1,2048,512) fp32
  const float* W    = (const float*)d_in[1];  // (4,512) fp32
  const float* P    = (const float*)d_in[2];  // (3072,512) fp32
  const float* bias = (const float*)d_in[3];  // (512,) fp32
  float* out = (float*)d_out;                 // (4,1,8192,512) fp32

  unsigned short* XbfZ = (unsigned short*)d_ws;               // 4*2049*512 = 4,196,352 shorts
  unsigned short* Ball = XbfZ + (size_t)4 * NROWS_X * 512;    // 4*512*2048 = 4,194,304 shorts
  // total need ~= 25.2 MB (well under the harness workspace)

  prep<<<2305, 256, 0, stream>>>(x, W, P, XbfZ, Ball);
  gemmcs<<<dim3(256), dim3(512), 0, stream>>>(XbfZ, Ball, W, bias, out);
}

// Round 5
// 175.838 us; speedup vs baseline: 1.0759x; 1.0759x over previous
//
#include <hip/hip_runtime.h>
#include <cstdint>
#include <cstddef>

// (B,H,L,D,k) = (4,1,2048,512,4), SHIFTS = {1,2,4}
// Folded: out[(b,l,j),d] = sum_c v[c]*Qj[c,d]               (diff, K=512)
//                        + sum_{si,c} silu(v[c]*W[j,(c-s)%512]) * Psilu[si,c,d]  (K=1536)
// v = x[b,l-1] for j<3, x[b,l] for j==3.
// Round 8: revert to round-3 base (fused prep + 2-barrier gemm, 175.6 us) and deepen
// the gemm load pipeline: 3-deep A ring + 2-deep B (160 KB LDS exactly), steady-state
// vmcnt(8) so both operands have ~2 full K-steps in flight; MFMA clusters reordered
// k-outermost (16 independent MFMAs before any same-acc dependent one).
#define D_DIM 512
#define L_DIM 2048
#define KB_DIM 2048    // 512 diff + 3*512 silu
#define KS_DIM 1536
#define NROWS_X 2049   // per-b rows in XbfZ; row 0 is zeros (the l=-1 pad)
#define M_TOT 32768

typedef __bf16 bf16x8 __attribute__((ext_vector_type(8)));
typedef float  f32x4  __attribute__((ext_vector_type(4)));

__device__ __forceinline__ unsigned f2bf(float f) {
  unsigned u = __float_as_uint(f);
  u += 0x7FFF + ((u >> 16) & 1);   // RNE
  return u >> 16;
}
__device__ __forceinline__ float bf2f(unsigned short u) {
  return __uint_as_float(((unsigned)u) << 16);
}
__device__ __forceinline__ void gld_lds16(const void* g, void* l) {
  __builtin_amdgcn_global_load_lds((const __attribute__((address_space(1))) void*)g,
                                   (__attribute__((address_space(3))) void*)l,
                                   16, 0, 0);
}

// ---------------- fused prepass: conv(x)->XbfZ + GS silu rows  AND  build_B ----------
// grid 2304 x 256: blocks [0,2048) = conv/GS path (4 x-rows each);
//                  blocks [2048,2304) = build_B path (Ball).
__global__ __launch_bounds__(256) void prep(
    const float* __restrict__ x, const float* __restrict__ W, const float* __restrict__ P,
    unsigned short* __restrict__ XbfZ, unsigned short* __restrict__ Ball,
    unsigned short* __restrict__ GS, int doGS) {
  __shared__ unsigned short WtabL[6144];   // [j*3+si][c] bf16(W[j,(c-s)&511])
  const int tid = threadIdx.x;

  if (blockIdx.x < 2048) {
    // ---------------- conv + GS path ----------------
    for (int i = tid; i < 6144; i += 256) {
      const int c = i & 511; const int rest = i >> 9;   // rest = j*3+si
      const int si = rest % 3; const int jj = rest / 3;
      WtabL[i] = (unsigned short)f2bf(W[jj * 512 + ((c - (1 << si)) & 511)]);
    }
    __syncthreads();

    const int r = tid >> 6, lane = tid & 63;
    const int gr = blockIdx.x * 4 + r;          // x-row index 0..8191
    const int b = gr >> 11, l = gr & 2047;

    // load x[b,l] (8 floats per lane), convert to bf16
    const float4* xr = reinterpret_cast<const float4*>(x) + ((size_t)(b * L_DIM + l)) * 128 + lane * 2;
    const float4 v0 = xr[0], v1 = xr[1];
    union U { uint4 q; unsigned short s[8]; };
    U va;
    va.q.x = f2bf(v0.x) | (f2bf(v0.y) << 16);
    va.q.y = f2bf(v0.z) | (f2bf(v0.w) << 16);
    va.q.z = f2bf(v1.x) | (f2bf(v1.y) << 16);
    va.q.w = f2bf(v1.z) | (f2bf(v1.w) << 16);
    *reinterpret_cast<uint4*>(XbfZ + ((size_t)(b * NROWS_X + l + 1)) * 512 + lane * 8) = va.q;

    if (doGS) {
      #pragma unroll
      for (int j = 0; j < 4; ++j) {
        // dest GS row: j<3 -> (j,b,l+1) (only if l+1<2048); j==3 -> (3,b,l)
        const int lam = (j < 3) ? (l + 1) : l;
        const bool wr = (j == 3) || (l < 2047);
        unsigned short* o = GS + ((size_t)((j * 4 + b) * L_DIM + lam)) * KS_DIM + lane * 8;
        #pragma unroll
        for (int si = 0; si < 3; ++si) {
          U wa;
          wa.q = *reinterpret_cast<const uint4*>(&WtabL[(j * 3 + si) * 512 + lane * 8]);
          unsigned res[4];
          #pragma unroll
          for (int e = 0; e < 4; ++e) {
            float s0 = bf2f(va.s[2 * e])     * bf2f(wa.s[2 * e]);
            float s1 = bf2f(va.s[2 * e + 1]) * bf2f(wa.s[2 * e + 1]);
            float g0 = s0 * __builtin_amdgcn_rcpf(1.f + __expf(-s0));
            float g1 = s1 * __builtin_amdgcn_rcpf(1.f + __expf(-s1));
            res[e] = f2bf(g0) | (f2bf(g1) << 16);
          }
          if (wr) {
            uint4 ov = {res[0], res[1], res[2], res[3]};
            *reinterpret_cast<uint4*>(o + si * 512) = ov;
          }
        }
      }
    }
    // per-b zero rows (row 0 of XbfZ, lambda=0 GS rows for j<3): one x-row (l==2047) per b
    if (l == 2047) {
      const uint4 z = {0u, 0u, 0u, 0u};
      *reinterpret_cast<uint4*>(XbfZ + ((size_t)(b * NROWS_X)) * 512 + lane * 8) = z;
      if (doGS) {
        #pragma unroll
        for (int j = 0; j < 3; ++j)
          #pragma unroll
          for (int si = 0; si < 3; ++si)
            *reinterpret_cast<uint4*>(GS + ((size_t)((j * 4 + b) * L_DIM)) * KS_DIM + si * 512 + lane * 8) = z;
      }
    }
    return;
  }

  // ---------------- build_B path (Ball) ----------------
  const int bx = blockIdx.x - 2048;      // 0..255
  const int j = bx >> 6, dt = (bx >> 3) & 7, ct = bx & 7;
  const int d = dt * 64 + (tid & 63);
  const int cbase = ct * 64 + (tid >> 6) * 16;
  unsigned short bufd[16];
  unsigned short bufs[3][16];
  #pragma unroll
  for (int cc = 0; cc < 16; ++cc) {
    const int c = cbase + cc;
    float qd = 0.f;
    #pragma unroll
    for (int si = 0; si < 3; ++si) {
      const int s = 1 << si;
      const int cm = (c - s) & 511, cp = (c + s) & 511;
      qd += W[j * 512 + cm] * P[((size_t)(2 * si) * 512 + c) * 512 + d]
          - W[j * 512 + cp] * P[((size_t)(2 * si) * 512 + cp) * 512 + d];
      bufs[si][cc] = (unsigned short)f2bf(P[((size_t)(2 * si + 1) * 512 + c) * 512 + d]);
    }
    bufd[cc] = (unsigned short)f2bf(qd);
  }
  unsigned short* row = Ball + (size_t)(j * 512 + d) * KB_DIM;
  *reinterpret_cast<uint4*>(&row[cbase])     = *reinterpret_cast<uint4*>(&bufd[0]);
  *reinterpret_cast<uint4*>(&row[cbase + 8]) = *reinterpret_cast<uint4*>(&bufd[8]);
  #pragma unroll
  for (int si = 0; si < 3; ++si) {
    *reinterpret_cast<uint4*>(&row[512 + si * 512 + cbase])     = *reinterpret_cast<uint4*>(&bufs[si][0]);
    *reinterpret_cast<uint4*>(&row[512 + si * 512 + cbase + 8]) = *reinterpret_cast<uint4*>(&bufs[si][8]);
  }
}

// ---------------- main GEMM: 256x256, BK=64, 8 waves, 3-deep A ring, vmcnt(8) --------
#define BARR asm volatile("s_barrier" ::: "memory")
#define VMW(N) asm volatile("s_waitcnt vmcnt(" #N ")" ::: "memory")

#define READ_A(MH, AP) do { \
  _Pragma("unroll") \
  for (int mf = 0; mf < 4; ++mf) { \
    a[mf][0] = __builtin_bit_cast(bf16x8, *reinterpret_cast<const uint4*>(&(AP)[aRow[mf] + (MH)*4096 + p0])); \
    a[mf][1] = __builtin_bit_cast(bf16x8, *reinterpret_cast<const uint4*>(&(AP)[aRow[mf] + (MH)*4096 + p1])); \
  } } while (0)

#define READ_B(NH, BP, BB) do { \
  _Pragma("unroll") \
  for (int nf = 0; nf < 2; ++nf) { \
    BB[nf][0] = __builtin_bit_cast(bf16x8, *reinterpret_cast<const uint4*>(&(BP)[bRow[nf] + (NH)*2048 + p0])); \
    BB[nf][1] = __builtin_bit_cast(bf16x8, *reinterpret_cast<const uint4*>(&(BP)[bRow[nf] + (NH)*2048 + p1])); \
  } } while (0)

// k-outermost: 16 independent MFMAs (kc=0) before any same-acc dependent one (kc=1).
#define MFMA_ROW(MH) do { \
  _Pragma("unroll") \
  for (int kc = 0; kc < 2; ++kc) { \
    _Pragma("unroll") \
    for (int mf = 0; mf < 4; ++mf) { \
      acc[(MH)*4+mf][0] = __builtin_amdgcn_mfma_f32_16x16x32_bf16(a[mf][kc], b0[0][kc], acc[(MH)*4+mf][0], 0, 0, 0); \
      acc[(MH)*4+mf][1] = __builtin_amdgcn_mfma_f32_16x16x32_bf16(a[mf][kc], b0[1][kc], acc[(MH)*4+mf][1], 0, 0, 0); \
      acc[(MH)*4+mf][2] = __builtin_amdgcn_mfma_f32_16x16x32_bf16(a[mf][kc], b1[0][kc], acc[(MH)*4+mf][2], 0, 0, 0); \
      acc[(MH)*4+mf][3] = __builtin_amdgcn_mfma_f32_16x16x32_bf16(a[mf][kc], b1[1][kc], acc[(MH)*4+mf][3], 0, 0, 0); \
    } } } while (0)

__global__ __launch_bounds__(512, 2) void gemm8(
    const unsigned short* __restrict__ XbfZ, const unsigned short* __restrict__ GS,
    const unsigned short* __restrict__ Ball, const float* __restrict__ bias,
    float* __restrict__ out) {
  // Each buffer: 256 rows x 64 k x bf16 = 32 KB (row = 128 B = 8 chunks of 16 B).
  // Chunk XOR swizzle: chunk c of row r stored at pos p = c ^ (r&7).
  // A: 3-buffer ring (96 KB); B: 2-buffer (64 KB). 160 KB total = gfx950 LDS max.
  __shared__ alignas(16) unsigned short A_lds[3][16384];
  __shared__ alignas(16) unsigned short B_lds[2][16384];

  const int tid = threadIdx.x;
  // Bijective XCD swizzle (256 blocks, 8 XCDs): XCD x gets wids x*32..x*32+31.
  const int bid = blockIdx.x;
  const int wid = (bid & 7) * 32 + (bid >> 3);
  const int mtile = wid >> 1;            // 0..127
  const int ntile = wid & 1;             // 0..1
  const int j  = mtile >> 5;
  const int b  = (mtile >> 3) & 3;
  const int l0 = (mtile & 7) * 256;
  const int n0 = ntile * 256;
  const size_t mbase = (size_t)((j * 4 + b) * L_DIM + l0);

  // ---- staging geometry: thread covers slots tid and tid+512 of each half-tile.
  // slot s: row = s>>3, pos = s&7; global chunk c = pos ^ (row&7) (same for both slots).
  const int srow = tid >> 3;             // 0..63
  const int c8   = (tid & 7) ^ (srow & 7);
  const unsigned short* pXd = XbfZ + ((size_t)(b * NROWS_X + (j == 3) + l0 + srow)) * 512 + c8 * 8;
  const unsigned short* pGS = GS + (mbase + srow) * (size_t)KS_DIM + c8 * 8;
  const unsigned short* pB  = Ball + ((size_t)(j * 512 + n0 + srow)) * KB_DIM + c8 * 8;
  const int ldsSlot = tid * 8;           // shorts; second slot at +4096

  auto stageA = [&](int TT, int bufi) {  // 4 glds: both halves of A-tile TT -> ring buf
    #pragma unroll
    for (int h = 0; h < 2; ++h) {
      unsigned short* dst = &A_lds[bufi][h * 8192 + ldsSlot];
      if (TT < 8) {
        const unsigned short* s = pXd + (size_t)h * 128 * 512 + TT * 64;
        gld_lds16(s, dst);
        gld_lds16(s + 64 * 512, dst + 4096);
      } else {
        const unsigned short* s = pGS + (size_t)h * 128 * KS_DIM + (TT - 8) * 64;
        gld_lds16(s, dst);
        gld_lds16(s + 64 * KS_DIM, dst + 4096);
      }
    }
  };
  auto stageB = [&](int TT, int bufi) {  // 4 glds
    #pragma unroll
    for (int h = 0; h < 2; ++h) {
      const unsigned short* s = pB + (size_t)h * 128 * KB_DIM + TT * 64;
      unsigned short* dst = &B_lds[bufi][h * 8192 + ldsSlot];
      gld_lds16(s, dst);
      gld_lds16(s + 64 * KB_DIM, dst + 4096);
    }
  };

  // ---- MFMA frag geometry: 8 waves 2(M) x 4(N); per-wave output 128x64 ----
  const int lane = tid & 63, wv = tid >> 6;
  const int wm = wv >> 2, wn = wv & 3;
  const int l16 = lane & 15, quad = lane >> 4;
  const int p0 = ((quad)     ^ (l16 & 7)) * 8;   // k-chunk ks=0 (after XOR swizzle)
  const int p1 = ((quad + 4) ^ (l16 & 7)) * 8;   // k-chunk ks=1
  int aRow[4], bRow[2];
  #pragma unroll
  for (int mf = 0; mf < 4; ++mf) aRow[mf] = (wm * 128 + mf * 16 + l16) * 64;
  #pragma unroll
  for (int nf = 0; nf < 2; ++nf) bRow[nf] = (wn * 64 + nf * 16 + l16) * 64;

  f32x4 acc[8][4];
  #pragma unroll
  for (int i = 0; i < 8; ++i)
    #pragma unroll
    for (int n = 0; n < 4; ++n)
      acc[i][n] = f32x4{0.f, 0.f, 0.f, 0.f};

  bf16x8 a[4][2], b0[2][2], b1[2][2];

  // ---- prologue: issue A(0),B(0),A(1),B(1) (16 loads); wait all but 8 youngest ----
  stageA(0, 0);
  stageB(0, 0);
  stageA(1, 1);
  stageB(1, 1);
  VMW(8);          // A(0)+B(0) landed; A(1),B(1) still in flight
  BARR;

  // Steady state (tile T, cur=T&1, ra = T%3 A-ring slot):
  //   ph0: stage A(T+2) -> ring slot (T+2)%3 ; read A-h0 + ALL B ; MFMA row 0
  //        BARR   [all waves' B-reads reg-resident before stageB(T+2) writes cur]
  //   ph1: stage B(T+2) -> cur ; read A-h1 ; MFMA row 1
  //        VMW(8) [A(T+1),B(T+1) landed; A(T+2),B(T+2) = 8 youngest in flight] ; BARR
  int ra = 0;                 // A ring slot of tile T
  for (int T = 0; T < 32; ++T) {
    const int cur = T & 1;
    const int rs = (ra >= 1) ? (ra - 1) : 2;    // (ra+2)%3 = slot for A(T+2)
    const unsigned short* Ac = A_lds[ra];
    const unsigned short* Bc = B_lds[cur];
    // ---- phase 0 ----
    if (T + 2 < 32) stageA(T + 2, rs);
    READ_A(0, Ac);
    READ_B(0, Bc, b0);
    READ_B(1, Bc, b1);
    __builtin_amdgcn_s_setprio(1);
    MFMA_ROW(0);
    __builtin_amdgcn_s_setprio(0);
    BARR;
    // ---- phase 1 ----
    if (T + 2 < 32) stageB(T + 2, cur);
    READ_A(1, Ac);
    __builtin_amdgcn_s_setprio(1);
    MFMA_ROW(1);
    __builtin_amdgcn_s_setprio(0);
    if (T < 30) {
      VMW(8);
      BARR;
    } else if (T == 30) {
      VMW(0);          // tail: tile 31 must fully land (nothing issued behind it)
      BARR;
    }
    ra = (ra >= 2) ? 0 : (ra + 1);
  }

  // ---- epilogue: C/D col = lane&15 (N), row = quad*4+reg (M) ----
  #pragma unroll
  for (int nfg = 0; nfg < 4; ++nfg) {
    const int d = n0 + wn * 64 + nfg * 16 + l16;
    const float bv = bias[d];
    #pragma unroll
    for (int mfg = 0; mfg < 8; ++mfg) {
      const int lrow = l0 + wm * 128 + mfg * 16 + quad * 4;
      #pragma unroll
      for (int rg = 0; rg < 4; ++rg) {
        out[((size_t)(b * L_DIM + lrow + rg) * 4 + j) * D_DIM + d] = acc[mfg][nfg][rg] + bv;
      }
    }
  }
}

// ---------------- fallback: fused kernel (used if ws too small) ----------------
__global__ __launch_bounds__(256, 2) void fused_gemm(
    const unsigned short* __restrict__ XbfZ, const unsigned short* __restrict__ Ball,
    const float* __restrict__ W, const float* __restrict__ bias,
    float* __restrict__ out) {
  __shared__ alignas(16) unsigned short Vt[2][4096];
  __shared__ alignas(16) unsigned short Bt[2][8192];
  __shared__ alignas(16) unsigned short At[128 * 40];
  __shared__ alignas(16) unsigned short Wr[3 * 512];

  const int tid = threadIdx.x;
  const int nt = blockIdx.x & 1;
  const int mt = blockIdx.x >> 1;
  const int j  = mt >> 6;
  const int b  = (mt >> 4) & 3;
  const int lt = mt & 15;
  const int l0 = lt * 128;
  const int n0 = nt * 256;
  const int base_l = l0 - ((j == 3) ? 0 : 1);

  #pragma unroll
  for (int i = 0; i < 6; ++i) {
    const int idx = tid + i * 256;
    const int si = idx >> 9, c = idx & 511, s = 1 << si;
    Wr[idx] = (unsigned short)f2bf(W[j * 512 + ((c - s) & 511)]);
  }

  const int lane = tid & 63, wv = tid >> 6;
  const int qv = (lane & 3) ^ ((lane >> 4) & 3);
  const int rsub = lane >> 2;
  const unsigned short* gA0 = XbfZ + ((size_t)(b * NROWS_X + 1 + base_l + (wv * 2) * 16 + rsub)) * 512 + qv * 8;
  const unsigned short* gA1 = gA0 + (size_t)16 * 512;
  const unsigned short* gB[4];
  #pragma unroll
  for (int pi = 0; pi < 4; ++pi)
    gB[pi] = Ball + (size_t)(j * 512 + n0 + (wv * 4 + pi) * 16 + rsub) * KB_DIM + qv * 8;
  const int vOff0 = wv * 1024 + lane * 8;
  const int bOff0 = wv * 2048 + lane * 8;

  const int am = tid >> 1;
  const int akh = (tid & 1) * 16;
  const int ch0 = (tid & 1) * 2;
  const int sswz = (am >> 2) & 3;
  unsigned short* aDst = &At[am * 40 + akh];

  const int l16 = lane & 15, quad = lane >> 4;
  const int wm = wv >> 1, wn = wv & 1;
  const int fsw = (l16 >> 2) & 3;
  const int aVoff = (wm * 64 + l16) * 32 + ((quad ^ fsw)) * 8;
  const int aSoff = (wm * 64 + l16) * 40 + quad * 8;
  const int bOffF = (wn * 128 + l16) * 32 + ((quad ^ fsw)) * 8;

  f32x4 acc[4][8];
  #pragma unroll
  for (int i = 0; i < 4; ++i)
    #pragma unroll
    for (int n = 0; n < 8; ++n)
      acc[i][n] = f32x4{0.f, 0.f, 0.f, 0.f};

  {
    gld_lds16(gA0, &Vt[0][vOff0]);
    gld_lds16(gA1, &Vt[0][vOff0 + 512]);
    #pragma unroll
    for (int pi = 0; pi < 4; ++pi)
      gld_lds16(gB[pi], &Bt[0][bOff0 + pi * 512]);
  }

  for (int it = 0; it < 64; ++it) {
    const int buf = it & 1;
    const int kk0 = it * 32;
    const int gi = kk0 >> 9;

    __syncthreads();

    if (it + 1 < 64) {
      const int nk = kk0 + 32;
      const int nv = nk & 511;
      gld_lds16(gA0 + nv, &Vt[buf ^ 1][vOff0]);
      gld_lds16(gA1 + nv, &Vt[buf ^ 1][vOff0 + 512]);
      #pragma unroll
      for (int pi = 0; pi < 4; ++pi)
        gld_lds16(gB[pi] + nk, &Bt[buf ^ 1][bOff0 + pi * 512]);
    }

    bf16x8 af[4], bfr[8];
    if (gi == 0) {
      #pragma unroll
      for (int mi = 0; mi < 4; ++mi) {
        uint4 r = *reinterpret_cast<const uint4*>(&Vt[buf][aVoff + mi * 512]);
        af[mi] = __builtin_bit_cast(bf16x8, r);
      }
    } else {
      const int si = gi - 1;
      const int ccbase = (kk0 & 511) + akh;
      uint4 v0 = *reinterpret_cast<const uint4*>(&Vt[buf][(am * 4 + ((ch0)     ^ sswz)) * 8]);
      uint4 v1 = *reinterpret_cast<const uint4*>(&Vt[buf][(am * 4 + ((ch0 + 1) ^ sswz)) * 8]);
      uint4 w0 = *reinterpret_cast<const uint4*>(&Wr[si * 512 + ccbase]);
      uint4 w1 = *reinterpret_cast<const uint4*>(&Wr[si * 512 + ccbase + 8]);
      union U { uint4 q[2]; unsigned short s[16]; };
      U va, wa; va.q[0] = v0; va.q[1] = v1; wa.q[0] = w0; wa.q[1] = w1;
      unsigned res[8];
      #pragma unroll
      for (int e = 0; e < 8; ++e) {
        float s0 = bf2f(va.s[2 * e])     * bf2f(wa.s[2 * e]);
        float s1 = bf2f(va.s[2 * e + 1]) * bf2f(wa.s[2 * e + 1]);
        float g0 = s0 * __builtin_amdgcn_rcpf(1.f + __expf(-s0));
        float g1 = s1 * __builtin_amdgcn_rcpf(1.f + __expf(-s1));
        res[e] = f2bf(g0) | (f2bf(g1) << 16);
      }
      uint4 o0 = {res[0], res[1], res[2], res[3]};
      uint4 o1 = {res[4], res[5], res[6], res[7]};
      *reinterpret_cast<uint4*>(aDst) = o0;
      *reinterpret_cast<uint4*>(aDst + 8) = o1;
      __syncthreads();
      #pragma unroll
      for (int mi = 0; mi < 4; ++mi) {
        uint4 r = *reinterpret_cast<const uint4*>(&At[aSoff + mi * 640]);
        af[mi] = __builtin_bit_cast(bf16x8, r);
      }
    }
    #pragma unroll
    for (int ni = 0; ni < 8; ++ni) {
      uint4 r = *reinterpret_cast<const uint4*>(&Bt[buf][bOffF + ni * 512]);
      bfr[ni] = __builtin_bit_cast(bf16x8, r);
    }
    #pragma unroll
    for (int mi = 0; mi < 4; ++mi)
      #pragma unroll
      for (int ni = 0; ni < 8; ++ni)
        acc[mi][ni] = __builtin_amdgcn_mfma_f32_16x16x32_bf16(af[mi], bfr[ni], acc[mi][ni], 0, 0, 0);
  }

  #pragma unroll
  for (int ni = 0; ni < 8; ++ni) {
    const int d = n0 + wn * 128 + ni * 16 + l16;
    const float bv = bias[d];
    #pragma unroll
    for (int mi = 0; mi < 4; ++mi) {
      const int lrow = l0 + wm * 64 + mi * 16 + quad * 4;
      #pragma unroll
      for (int rg = 0; rg < 4; ++rg) {
        out[((size_t)(b * L_DIM + lrow + rg) * 4 + j) * D_DIM + d] = acc[mi][ni][rg] + bv;
      }
    }
  }
}

extern "C" void kernel_launch(void* const* d_in, const int* in_sizes, int n_in,
                              void* d_out, int out_size, void* d_ws, size_t ws_size,
                              hipStream_t stream) {
  const float* x    = (const float*)d_in[0];  // (4,1,2048,512) fp32
  const float* W    = (const float*)d_in[1];  // (4,512) fp32
  const float* P    = (const float*)d_in[2];  // (3072,512) fp32
  const float* bias = (const float*)d_in[3];  // (512,) fp32
  float* out = (float*)d_out;                 // (4,1,8192,512) fp32

  unsigned short* XbfZ = (unsigned short*)d_ws;                       // 4*2049*512   = 4,196,352 shorts
  unsigned short* Ball = XbfZ + (size_t)4 * NROWS_X * 512;            // 4*512*2048   = 4,194,304
  unsigned short* GS   = Ball + (size_t)4 * 512 * KB_DIM + 6144;      // 32768*1536   = 50,331,648
  const size_t need_bytes =
      ((size_t)4 * NROWS_X * 512 + (size_t)4 * 512 * KB_DIM + 6144 +
       (size_t)M_TOT * KS_DIM) * 2;
  const bool primary = ws_size >= need_bytes;

  prep<<<2304, 256, 0, stream>>>(x, W, P, XbfZ, Ball, GS, primary ? 1 : 0);
  if (primary) {
    gemm8<<<dim3(256), dim3(512), 0, stream>>>(XbfZ, GS, Ball, bias, out);
  } else {
    fused_gemm<<<512, 256, 0, stream>>>(XbfZ, Ball, W, bias, out);
  }
}